// Round 1
// baseline (312.063 us; speedup 1.0000x reference)
//
#include <hip/hip_runtime.h>
#include <hip/hip_fp16.h>

typedef float    f32x4 __attribute__((ext_vector_type(4)));
typedef _Float16 f16x4 __attribute__((ext_vector_type(4)));
typedef _Float16 f16x8 __attribute__((ext_vector_type(8)));

#define BS 8
#define NN 2048
#define DK 128
#define DM 64

// ---------------- prep: mean over N ----------------
__global__ void mean_k(const float* __restrict__ qt, float* __restrict__ bar) {
  int b = blockIdx.x;
  int t = threadIdx.x;
  int c = t & 127, h = t >> 7;
  const float* p = qt + ((size_t)b * NN + h * 1024) * DK + c;
  float s = 0.f;
#pragma unroll 8
  for (int n = 0; n < 1024; ++n) s += p[(size_t)n * DK];
  __shared__ float red[256];
  red[t] = s;
  __syncthreads();
  if (t < 128) bar[b * DK + t] = (red[t] + red[t + 128]) * (1.0f / 2048.0f);
}

// ---------------- prep: prior = softmax(kernel @ bar^T, axis=1(batch)) ----------------
__global__ void prior_k(const float* __restrict__ kern, const float* __restrict__ bar,
                        float* __restrict__ prior) {
  int t = threadIdx.x;
  __shared__ float lg[16], ex[16];
  if (t < 16) {
    int m = t >> 3, b = t & 7;
    float s = 0.f;
    for (int c = 0; c < DK; ++c) s += kern[m * DK + c] * bar[b * DK + c];
    lg[t] = s;
  }
  __syncthreads();
  if (t < 16) {
    int m = t >> 3;
    float mx = lg[m * 8];
    for (int i = 1; i < 8; ++i) mx = fmaxf(mx, lg[m * 8 + i]);
    ex[t] = __expf(lg[t] - mx);
  }
  __syncthreads();
  if (t < 16) {
    int m = t >> 3;
    float sm = 0.f;
    for (int i = 0; i < 8; ++i) sm += ex[m * 8 + i];
    prior[t] = ex[t] / sm;  // flat[m*8+b]; attn reads flat[b*2+m] (TF reshape quirk)
  }
}

// ---------------- prep: f32 -> f16 (optional scale) ----------------
__global__ void cvt_k(const float* __restrict__ src, _Float16* __restrict__ dst, float scale) {
  size_t i = ((size_t)blockIdx.x * 256 + threadIdx.x) * 4;
  f32x4 v = *(const f32x4*)(src + i);
  f16x4 h;
  h[0] = (_Float16)(v[0] * scale);
  h[1] = (_Float16)(v[1] * scale);
  h[2] = (_Float16)(v[2] * scale);
  h[3] = (_Float16)(v[3] * scale);
  *(f16x4*)(dst + i) = h;
}

// ---------------- prep: V (2048x128) -> V^T (128x2048) f16, per batch ----------------
__global__ void tpose_k(const float* __restrict__ vt, _Float16* __restrict__ vT) {
  int b = blockIdx.z;
  int j0 = blockIdx.x * 32, c0 = blockIdx.y * 32;
  int tx = threadIdx.x, ty = threadIdx.y;  // 32 x 8
  __shared__ float tile[32][33];
  const float* src = vt + ((size_t)b * NN + j0) * DK + c0;
#pragma unroll
  for (int i = 0; i < 4; ++i)
    tile[ty + 8 * i][tx] = src[(size_t)(ty + 8 * i) * DK + tx];
  __syncthreads();
  _Float16* dst = vT + ((size_t)b * DK + c0) * NN + j0;
#pragma unroll
  for (int i = 0; i < 4; ++i)
    dst[(size_t)(ty + 8 * i) * NN + tx] = (_Float16)tile[tx][ty + 8 * i];
}

// ---------------- main: mixture flash attention ----------------
// grid 1024: b = blk>>7, qtile = blk&127 (16 queries). 4 waves = 4-way key split.
// Per (b,m): Q/K are the contiguous (2048 x 64) slab at b*262144 + m*131072.
// S^T tile via mfma_16x16x32_f16 (A=K, B=Q^T); exp in-lane; P^T D-frag == B-operand
// of mfma_16x16x16f16 => PV (O^T = V^T P^T) with no cross-lane relayout.
__global__ __launch_bounds__(256) void attn_k(const _Float16* __restrict__ qh,
                                              const _Float16* __restrict__ kh,
                                              const _Float16* __restrict__ vT,
                                              const float* __restrict__ prior,
                                              float* __restrict__ out) {
  const int b = blockIdx.x >> 7;
  const int q0 = (blockIdx.x & 127) << 4;
  const int wv = threadIdx.x >> 6;
  const int lane = threadIdx.x & 63;
  const int quad = lane >> 4, l16 = lane & 15;
  const int k0 = wv * 512;

  const size_t bq = (size_t)b * (NN * DK);

  f16x8 qf[2][2];
#pragma unroll
  for (int m = 0; m < 2; ++m) {
    const _Float16* qp = qh + bq + (size_t)m * (1024 * DK) + (size_t)(q0 + l16) * DM + quad * 8;
    qf[m][0] = *(const f16x8*)(qp);
    qf[m][1] = *(const f16x8*)(qp + 32);
  }
  const _Float16* kp0 = kh + bq + (size_t)(k0 + l16) * DM + quad * 8;
  const _Float16* vp0 = vT + (size_t)b * (DK * NN) + (size_t)l16 * NN + k0 + quad * 4;

  const f32x4 z = {0.f, 0.f, 0.f, 0.f};
  f32x4 acc[2][8];
#pragma unroll
  for (int m = 0; m < 2; ++m)
#pragma unroll
    for (int cc = 0; cc < 8; ++cc) acc[m][cc] = z;
  float lp[2] = {0.f, 0.f};

  for (int kt = 0; kt < 32; ++kt) {
    const _Float16* kp = kp0 + (size_t)kt * (16 * DM);
    f16x8 kf[2][2];
    kf[0][0] = *(const f16x8*)(kp);
    kf[0][1] = *(const f16x8*)(kp + 32);
    kf[1][0] = *(const f16x8*)(kp + 1024 * DK);
    kf[1][1] = *(const f16x8*)(kp + 1024 * DK + 32);
    const _Float16* vp = vp0 + kt * 16;
    f16x4 vf[8];
#pragma unroll
    for (int cc = 0; cc < 8; ++cc) vf[cc] = *(const f16x4*)(vp + (size_t)cc * (16 * NN));
#pragma unroll
    for (int m = 0; m < 2; ++m) {
      f32x4 s = __builtin_amdgcn_mfma_f32_16x16x32_f16(kf[m][1], qf[m][1], z, 0, 0, 0);
      s = __builtin_amdgcn_mfma_f32_16x16x32_f16(kf[m][0], qf[m][0], s, 0, 0, 0);
      // temperature folded into qh; scores safe without max subtraction (|s| <~ 6)
      float p0 = __expf(s[0]), p1 = __expf(s[1]), p2 = __expf(s[2]), p3 = __expf(s[3]);
      lp[m] += (p0 + p1) + (p2 + p3);
      f16x4 pb;
      pb[0] = (_Float16)p0; pb[1] = (_Float16)p1;
      pb[2] = (_Float16)p2; pb[3] = (_Float16)p3;
#pragma unroll
      for (int cc = 0; cc < 8; ++cc)
        acc[m][cc] = __builtin_amdgcn_mfma_f32_16x16x16f16(vf[cc], pb, acc[m][cc], 0, 0, 0);
    }
  }

  // ---- merge 4 key-split waves via LDS atomics, normalize, store ----
  __shared__ float obuf[2][16][130];  // [m][q][c]; c=128 holds l; +130 stride de-conflicts
  for (int i = threadIdx.x; i < 2 * 16 * 130; i += 256) ((float*)obuf)[i] = 0.f;
  __syncthreads();
#pragma unroll
  for (int m = 0; m < 2; ++m) {
#pragma unroll
    for (int cc = 0; cc < 8; ++cc)
#pragma unroll
      for (int r = 0; r < 4; ++r)
        atomicAdd(&obuf[m][l16][cc * 16 + quad * 4 + r], acc[m][cc][r]);
    atomicAdd(&obuf[m][l16][128], lp[m]);
  }
  __syncthreads();
  const float w0 = prior[b * 2 + 0], w1 = prior[b * 2 + 1];
  const int qq = threadIdx.x >> 4;
  const int cb = (threadIdx.x & 15) * 8;
  const float r0 = w0 / obuf[0][qq][128];
  const float r1 = w1 / obuf[1][qq][128];
  float* op = out + ((size_t)b * NN + q0 + qq) * DK + cb;
  f32x4 o0, o1;
#pragma unroll
  for (int u = 0; u < 4; ++u) o0[u] = obuf[0][qq][cb + u] * r0 + obuf[1][qq][cb + u] * r1;
#pragma unroll
  for (int u = 0; u < 4; ++u) o1[u] = obuf[0][qq][cb + 4 + u] * r0 + obuf[1][qq][cb + 4 + u] * r1;
  *(f32x4*)(op) = o0;
  *(f32x4*)(op + 4) = o1;
}

extern "C" void kernel_launch(void* const* d_in, const int* in_sizes, int n_in,
                              void* d_out, int out_size, void* d_ws, size_t ws_size,
                              hipStream_t stream) {
  const float* qt = (const float*)d_in[0];
  const float* kt = (const float*)d_in[1];
  const float* vt = (const float*)d_in[2];
  const float* kern = (const float*)d_in[3];
  float* out = (float*)d_out;

  char* ws = (char*)d_ws;
  float* prior = (float*)ws;                 // 16 floats
  float* bar = (float*)ws + 64;              // 1024 floats
  _Float16* qhp = (_Float16*)(ws + 8192);    // 2M halfs (4 MB)
  _Float16* khp = qhp + (size_t)BS * NN * DK;
  _Float16* vTp = khp + (size_t)BS * NN * DK;

  const float invTemp = 0.08838834764831845f;  // 1/sqrt(128)

  mean_k<<<dim3(8), dim3(256), 0, stream>>>(qt, bar);
  prior_k<<<dim3(1), dim3(64), 0, stream>>>(kern, bar, prior);
  cvt_k<<<dim3(2048), dim3(256), 0, stream>>>(qt, qhp, invTemp);
  cvt_k<<<dim3(2048), dim3(256), 0, stream>>>(kt, khp, 1.0f);
  tpose_k<<<dim3(64, 4, 8), dim3(32, 8), 0, stream>>>(vt, vTp);
  attn_k<<<dim3(1024), dim3(256), 0, stream>>>(qhp, khp, vTp, prior, out);
}

// Round 3
// 263.679 us; speedup vs baseline: 1.1835x; 1.1835x over previous
//
#include <hip/hip_runtime.h>
#include <hip/hip_fp16.h>

typedef float    f32x4 __attribute__((ext_vector_type(4)));
typedef _Float16 f16x2 __attribute__((ext_vector_type(2)));
typedef _Float16 f16x4 __attribute__((ext_vector_type(4)));
typedef _Float16 f16x8 __attribute__((ext_vector_type(8)));

#define BS 8
#define NN 2048
#define DK 128
#define DM 64
// log2(e) / sqrt(128): folds softmax temperature AND exp->exp2 conversion into Q
#define QSCALE 0.12751744116926208f

#define MFMA32(a, b, c) __builtin_amdgcn_mfma_f32_16x16x32_f16((a), (b), (c), 0, 0, 0)
#define EXP2(x) __builtin_amdgcn_exp2f(x)

__device__ __forceinline__ f16x2 pkrtz(float x, float y) {
  return __builtin_bit_cast(f16x2, __builtin_amdgcn_cvt_pkrtz(x, y));
}

// ---------------- prep: mean over N ----------------
__global__ void mean_k(const float* __restrict__ qt, float* __restrict__ bar) {
  int b = blockIdx.x;
  int t = threadIdx.x;
  int c = t & 127, h = t >> 7;
  const float* p = qt + ((size_t)b * NN + h * 1024) * DK + c;
  float s = 0.f;
#pragma unroll 8
  for (int n = 0; n < 1024; ++n) s += p[(size_t)n * DK];
  __shared__ float red[256];
  red[t] = s;
  __syncthreads();
  if (t < 128) bar[b * DK + t] = (red[t] + red[t + 128]) * (1.0f / 2048.0f);
}

// ---------------- prep: prior = softmax(kernel @ bar^T, axis=1(batch)) ----------------
__global__ void prior_k(const float* __restrict__ kern, const float* __restrict__ bar,
                        float* __restrict__ prior) {
  int t = threadIdx.x;
  __shared__ float lg[16], ex[16];
  if (t < 16) {
    int m = t >> 3, b = t & 7;
    float s = 0.f;
    for (int c = 0; c < DK; ++c) s += kern[m * DK + c] * bar[b * DK + c];
    lg[t] = s;
  }
  __syncthreads();
  if (t < 16) {
    int m = t >> 3;
    float mx = lg[m * 8];
    for (int i = 1; i < 8; ++i) mx = fmaxf(mx, lg[m * 8 + i]);
    ex[t] = __expf(lg[t] - mx);
  }
  __syncthreads();
  if (t < 16) {
    int m = t >> 3;
    float sm = 0.f;
    for (int i = 0; i < 8; ++i) sm += ex[m * 8 + i];
    prior[t] = ex[t] / sm;  // flat[m*8+b]; attn reads flat[b*2+m] (TF reshape quirk)
  }
}

// ---------------- prep: K f32->f16 + V transpose, one launch ----------------
__global__ void kv_prep(const float* __restrict__ kt, _Float16* __restrict__ kh,
                        const float* __restrict__ vt, _Float16* __restrict__ vT) {
  __shared__ float tile[32][33];
  int blk = blockIdx.x;
  int t = threadIdx.x;
  if (blk < 2048) {
    size_t i = ((size_t)blk * 256 + t) * 4;
    f32x4 v = *(const f32x4*)(kt + i);
    f16x4 h;
    h[0] = (_Float16)v[0]; h[1] = (_Float16)v[1];
    h[2] = (_Float16)v[2]; h[3] = (_Float16)v[3];
    *(f16x4*)(kh + i) = h;
  } else {
    blk -= 2048;
    int b = blk >> 8;
    int j0 = (blk & 63) * 32, c0 = ((blk >> 6) & 3) * 32;
    int tx = t & 31, ty = t >> 5;
    const float* src = vt + ((size_t)b * NN + j0) * DK + c0;
#pragma unroll
    for (int i = 0; i < 4; ++i)
      tile[ty + 8 * i][tx] = src[(size_t)(ty + 8 * i) * DK + tx];
    __syncthreads();
    _Float16* dst = vT + ((size_t)b * DK + c0) * NN + j0;
#pragma unroll
    for (int i = 0; i < 4; ++i)
      dst[(size_t)(ty + 8 * i) * NN + tx] = (_Float16)tile[tx][ty + 8 * i];
  }
}

// ---------------- main: mixture flash attention ----------------
// grid 512: b = blk&7 (XCD-pins each batch's K/V to one L2), qb = blk>>3 (32 queries).
// 4 waves key-split (512 keys each), 32-key iterations.
// K rows loaded with perm(rho)=(rho>>2)*8+(rho&3) so two 16x16x32 S^T D-frags
// concatenate exactly into the 16x16x32 B-operand (k=quad*8+j) for PV -> PV at
// full-K MFMA rate and V A-frags are contiguous f16x8 (16B) loads.
// Row-sum l computed by a ones-A MFMA. exp2 with log2e folded into Q scale.
__global__ __launch_bounds__(256, 2) void attn_k(const float* __restrict__ qt,
                                                 const _Float16* __restrict__ kh,
                                                 const _Float16* __restrict__ vT,
                                                 const float* __restrict__ prior,
                                                 float* __restrict__ out) {
  const int b = blockIdx.x & 7;
  const int qb = blockIdx.x >> 3;
  const int wv = threadIdx.x >> 6;
  const int lane = threadIdx.x & 63;
  const int quad = lane >> 4, l16 = lane & 15;
  const int perm = ((l16 >> 2) << 3) | (l16 & 3);
  const size_t bq = (size_t)b * (NN * DK);

  // Q fragments: f32 load + scale + pack to f16 in-register (no Q prep kernel)
  f16x8 qf[2][2][2];  // [mix][qtile][chunk]
#pragma unroll
  for (int m = 0; m < 2; ++m)
#pragma unroll
    for (int u = 0; u < 2; ++u)
#pragma unroll
      for (int c = 0; c < 2; ++c) {
        const float* qp = qt + bq + (size_t)m * (1024 * DK) +
                          (size_t)(qb * 32 + u * 16 + l16) * DM + quad * 8 + c * 32;
        f32x4 v0 = *(const f32x4*)qp;
        f32x4 v1 = *(const f32x4*)(qp + 4);
        union { f16x8 v; f16x2 h[4]; } w;
        w.h[0] = pkrtz(v0[0] * QSCALE, v0[1] * QSCALE);
        w.h[1] = pkrtz(v0[2] * QSCALE, v0[3] * QSCALE);
        w.h[2] = pkrtz(v1[0] * QSCALE, v1[1] * QSCALE);
        w.h[3] = pkrtz(v1[2] * QSCALE, v1[3] * QSCALE);
        qf[m][u][c] = w.v;
      }

  const _Float16* kp = kh + bq + (size_t)(wv * 512 + perm) * DM + quad * 8;
  const _Float16* vp = vT + (size_t)b * (DK * NN) + (size_t)l16 * NN + wv * 512 + quad * 8;

  const f32x4 z = {0.f, 0.f, 0.f, 0.f};
  f32x4 acc[2][2][8];
  f32x4 lacc[2][2];
#pragma unroll
  for (int m = 0; m < 2; ++m)
#pragma unroll
    for (int u = 0; u < 2; ++u) {
      lacc[m][u] = z;
#pragma unroll
      for (int cc = 0; cc < 8; ++cc) acc[m][u][cc] = z;
    }
  const _Float16 one = (_Float16)1.0f;
  const f16x8 ones = {one, one, one, one, one, one, one, one};

  for (int kt = 0; kt < 16; ++kt) {
    // ---- QK: two 16-key subtiles (keys permuted for x32-PV concat) ----
    f32x4 s[2][2][2];  // [mix][qtile][subtile]
#pragma unroll
    for (int tt = 0; tt < 2; ++tt) {
      f16x8 k00 = *(const f16x8*)(kp + tt * 256);
      f16x8 k01 = *(const f16x8*)(kp + tt * 256 + 32);
      f16x8 k10 = *(const f16x8*)(kp + tt * 256 + 1024 * DK);
      f16x8 k11 = *(const f16x8*)(kp + tt * 256 + 1024 * DK + 32);
#pragma unroll
      for (int u = 0; u < 2; ++u) {
        s[0][u][tt] = MFMA32(k01, qf[0][u][1], MFMA32(k00, qf[0][u][0], z));
        s[1][u][tt] = MFMA32(k11, qf[1][u][1], MFMA32(k10, qf[1][u][0], z));
      }
    }
    // ---- V loads (independent; scheduler hoists under the QK MFMAs) ----
    f16x8 vf[8];
#pragma unroll
    for (int cc = 0; cc < 8; ++cc) vf[cc] = *(const f16x8*)(vp + (size_t)cc * (16 * NN));
    // ---- exp2 + pack; l via ones-MFMA ----
    f16x8 pb[2][2];
#pragma unroll
    for (int m = 0; m < 2; ++m)
#pragma unroll
      for (int u = 0; u < 2; ++u) {
        union { f16x8 v; f16x2 h[4]; } w;
        w.h[0] = pkrtz(EXP2(s[m][u][0][0]), EXP2(s[m][u][0][1]));
        w.h[1] = pkrtz(EXP2(s[m][u][0][2]), EXP2(s[m][u][0][3]));
        w.h[2] = pkrtz(EXP2(s[m][u][1][0]), EXP2(s[m][u][1][1]));
        w.h[3] = pkrtz(EXP2(s[m][u][1][2]), EXP2(s[m][u][1][3]));
        pb[m][u] = w.v;
        lacc[m][u] = MFMA32(ones, pb[m][u], lacc[m][u]);
      }
    // ---- PV at full-K x32 MFMA ----
#pragma unroll
    for (int cc = 0; cc < 8; ++cc)
#pragma unroll
      for (int m = 0; m < 2; ++m)
#pragma unroll
        for (int u = 0; u < 2; ++u)
          acc[m][u][cc] = MFMA32(vf[cc], pb[m][u], acc[m][u][cc]);
    kp += 32 * DM;
    vp += 32;
  }

  // ---- merge 4 key-split waves via LDS atomics, normalize, store ----
  __shared__ float obuf[2][32][130];  // [mix][q][ch]; slot 128 holds l
  for (int i = threadIdx.x; i < 2 * 32 * 130; i += 256) ((float*)obuf)[i] = 0.f;
  __syncthreads();
#pragma unroll
  for (int m = 0; m < 2; ++m)
#pragma unroll
    for (int u = 0; u < 2; ++u) {
#pragma unroll
      for (int cc = 0; cc < 8; ++cc)
#pragma unroll
        for (int r = 0; r < 4; ++r)
          atomicAdd(&obuf[m][u * 16 + l16][cc * 16 + quad * 4 + r], acc[m][u][cc][r]);
      if (quad == 0) atomicAdd(&obuf[m][u * 16 + l16][128], lacc[m][u][0]);
    }
  __syncthreads();
  const float w0 = prior[b * 2 + 0], w1 = prior[b * 2 + 1];
  const int q = threadIdx.x >> 3;
  const int c0 = (threadIdx.x & 7) * 16;
  const float r0 = w0 / obuf[0][q][128];
  const float r1 = w1 / obuf[1][q][128];
  float* op = out + ((size_t)b * NN + qb * 32 + q) * DK + c0;
#pragma unroll
  for (int g = 0; g < 4; ++g) {
    f32x4 o;
#pragma unroll
    for (int e = 0; e < 4; ++e)
      o[e] = obuf[0][q][c0 + g * 4 + e] * r0 + obuf[1][q][c0 + g * 4 + e] * r1;
    *(f32x4*)(op + g * 4) = o;
  }
}

extern "C" void kernel_launch(void* const* d_in, const int* in_sizes, int n_in,
                              void* d_out, int out_size, void* d_ws, size_t ws_size,
                              hipStream_t stream) {
  const float* qt = (const float*)d_in[0];
  const float* kt = (const float*)d_in[1];
  const float* vt = (const float*)d_in[2];
  const float* kern = (const float*)d_in[3];
  float* out = (float*)d_out;

  char* ws = (char*)d_ws;
  float* prior = (float*)ws;               // 16 floats
  float* bar = (float*)ws + 64;            // 1024 floats
  _Float16* khp = (_Float16*)(ws + 8192);  // 2M halfs (4 MB)
  _Float16* vTp = khp + (size_t)BS * NN * DK;

  mean_k<<<dim3(8), dim3(256), 0, stream>>>(qt, bar);
  prior_k<<<dim3(1), dim3(64), 0, stream>>>(kern, bar, prior);
  kv_prep<<<dim3(4096), dim3(256), 0, stream>>>(kt, khp, vt, vTp);
  attn_k<<<dim3(512), dim3(256), 0, stream>>>(qt, khp, vTp, prior, out);
}